// Round 7
// baseline (350.281 us; speedup 1.0000x reference)
//
#include <hip/hip_runtime.h>

// ---- problem constants (from reference) ----
#define TSTEPS 256
#define NPOP 4
#define NI 8
#define NO 4
#define NF 28            // NI + 2*NR + NO
#define RANDN 512
#define NBATCH 64
#define NSTATES (NPOP*RANDN)   // 2048
#define THREADS 768            // 12 waves: 0-7 main (recurrence), 8-11 helper (ext+y)
#define ALPHA 0.2f             // DT/TAU
#define ONEMA 0.8f

__device__ __forceinline__ float vexp2(float x) { return __builtin_amdgcn_exp2f(x); }
__device__ __forceinline__ float vrcp(float x)  { return __builtin_amdgcn_rcpf(x); }

// tanh(x) = 1 - 2/(e^{2x}+1)
__device__ __forceinline__ float ftanh(float x) {
    float t = vexp2(x * 2.885390081777927f);
    return __builtin_fmaf(-2.0f, vrcp(t + 1.0f), 1.0f);
}

template<int CTRL, int RM, int BM>
__device__ __forceinline__ float dpp_add(float x) {
    int v = __builtin_amdgcn_update_dpp(0, __float_as_int(x), CTRL, RM, BM, true);
    return x + __int_as_float(v);
}

// full wave64 sum -> valid in lane 63
__device__ __forceinline__ float wave_red_sum(float x) {
    x = dpp_add<0x111, 0xf, 0xf>(x);
    x = dpp_add<0x112, 0xf, 0xf>(x);
    x = dpp_add<0x114, 0xf, 0xf>(x);
    x = dpp_add<0x118, 0xf, 0xf>(x);
    x = dpp_add<0x142, 0xa, 0xf>(x);
    x = dpp_add<0x143, 0xc, 0xf>(x);
    return x;
}

// sum within each 8-lane group -> valid at lanes 8g+7
__device__ __forceinline__ float red8(float x) {
    x = dpp_add<0x111, 0xf, 0xf>(x);
    x = dpp_add<0x112, 0xf, 0xf>(x);
    x = dpp_add<0x114, 0xf, 0xf>(x);
    return x;
}

// barrier with LDS-only ordering (vmcnt stays in flight across it)
__device__ __forceinline__ void lds_barrier() {
    asm volatile("s_waitcnt lgkmcnt(0)\n\ts_barrier" ::: "memory");
}

__device__ __forceinline__ float readlane_f(float x, int l) {
    return __uint_as_float(__builtin_amdgcn_readlane(__float_as_uint(x), l));
}

__global__ __launch_bounds__(THREADS, 3)
void rnn_fused(
    const float* __restrict__ u,      // [B][T][NI]
    const float* __restrict__ G,      // [NPOP]
    const float* __restrict__ mu,     // [NPOP][NF]
    const float* __restrict__ C,      // [NPOP][NF][NF]
    const float* __restrict__ h0,     // [NPOP][RANDN]
    const float* __restrict__ nl,     // [NPOP][RANDN][NF]
    const float* __restrict__ nrec,   // [B][T][NPOP][RANDN]
    float* __restrict__ y)            // [B][T+1][NO]
{
    __shared__ float u_lds[TSTEPS * NI];                     // 8 KB
    __shared__ float c_lds[NPOP * NF * NF];                  // 12.25 KB
    __shared__ float mu_lds[NPOP * NF];
    __shared__ __align__(16) float ext_lds[4][NSTATES];      // 32 KB ring: ext_t = a*(drive+noise)
    __shared__ __align__(16) float phi_lds[2][NSTATES];      // 16 KB ring: phi_t
    __shared__ __align__(16) float part[2][8][8];            // kappa partials (8 main waves)
    __shared__ __align__(16) float ybuf[TSTEPS + 2][4][4];   // row 0 dummy; row t+1 = y_t partials

    const int tid  = threadIdx.x;
    const int b    = blockIdx.x;
    const int lane = tid & 63;
    const int wid  = tid >> 6;
    const bool is_main = (wid < 8);

    // ---- stage u[b] (512 float4) and C (784 float4) into LDS ----
    {
        const float4* src = (const float4*)(u + (size_t)b * TSTEPS * NI);
        if (tid < TSTEPS * NI / 4) ((float4*)u_lds)[tid] = src[tid];
    }
    {
        const float4* src = (const float4*)C;
        float4* dst = (float4*)c_lds;
        if (tid < NPOP * NF * NF / 4) dst[tid] = src[tid];
        int idx2 = tid + THREADS;
        if (idx2 < NPOP * NF * NF / 4) dst[idx2] = src[idx2];
    }
    if (tid < NPOP * NF) mu_lds[tid] = mu[tid];
    __syncthreads();

    float* yout = y + (size_t)b * (TSTEPS + 1) * NO;

    if (is_main) {
        // ============================ MAIN WAVES (8) ============================
        const int mm = tid;          // slot 0..511
        const int p  = mm >> 7;      // population
        const int s0 = mm * 4;       // 4 states per thread

        float w_p;
        {
            float g0 = G[0], g1 = G[1], g2 = G[2], g3 = G[3];
            float mx = fmaxf(fmaxf(g0, g1), fmaxf(g2, g3));
            const float L2E = 1.4426950408889634f;
            float e0 = vexp2((g0 - mx) * L2E), e1 = vexp2((g1 - mx) * L2E);
            float e2 = vexp2((g2 - mx) * L2E), e3 = vexp2((g3 - mx) * L2E);
            float inv = vrcp(e0 + e1 + e2 + e3);
            float ap = (p == 0) ? e0 : (p == 1) ? e1 : (p == 2) ? e2 : e3;
            w_p = ap * inv * (1.0f / (float)RANDN);
        }

        // WU[k][r] = alpha*U (f=8..15), WV[k][r] = w*V (f=16..23)
        float WU[4][8], WV[4][8];
        #pragma unroll
        for (int c = 0; c < 8; ++c) {
            float mU = mu_lds[p * NF + 8 + c], mV = mu_lds[p * NF + 16 + c];
            #pragma unroll
            for (int k = 0; k < 4; ++k) { WU[k][c] = mU; WV[k][c] = mV; }
        }
        #pragma unroll
        for (int pr = 0; pr < 2; ++pr) {
            float nlr[2][NF];
            #pragma unroll
            for (int kk = 0; kk < 2; ++kk) {
                const float4* src = (const float4*)(nl + (size_t)(s0 + pr * 2 + kk) * NF);
                #pragma unroll
                for (int q = 0; q < 7; ++q) {
                    float4 v = src[q];
                    nlr[kk][q*4+0] = v.x; nlr[kk][q*4+1] = v.y;
                    nlr[kk][q*4+2] = v.z; nlr[kk][q*4+3] = v.w;
                }
            }
            #pragma unroll
            for (int f = 0; f < 16; ++f) {
                const float4* cr = (const float4*)&c_lds[(p * NF + 8 + f) * NF];
                float crow[NF];
                #pragma unroll
                for (int q = 0; q < 7; ++q) {
                    float4 v = cr[q];
                    crow[q*4+0] = v.x; crow[q*4+1] = v.y;
                    crow[q*4+2] = v.z; crow[q*4+3] = v.w;
                }
                #pragma unroll
                for (int kk = 0; kk < 2; ++kk) {
                    float acc = (f < 8) ? WU[pr*2+kk][f] : WV[pr*2+kk][f-8];
                    #pragma unroll
                    for (int ss = 0; ss < NF; ++ss)
                        acc = __builtin_fmaf(crow[ss], nlr[kk][ss], acc);
                    if (f < 8) WU[pr*2+kk][f] = acc; else WV[pr*2+kk][f-8] = acc;
                }
            }
        }
        #pragma unroll
        for (int k = 0; k < 4; ++k) {
            #pragma unroll
            for (int c = 0; c < 8; ++c) { WU[k][c] *= ALPHA; WV[k][c] *= w_p; }
        }

        float h[4];
        {
            float4 v = *(const float4*)(h0 + s0);
            h[0]=v.x; h[1]=v.y; h[2]=v.z; h[3]=v.w;
        }
        __syncthreads();   // helpers have written ext_0, ext_1

        const int s2addr = ((lane & 7) << 3) | (lane >> 3);  // part[w=lane&7][r=lane>>3]
        float4 eA = *(const float4*)&ext_lds[0][s0];         // ext_0
        float4 eB;
        __builtin_amdgcn_s_setprio(1);

        auto MBODY = [&](int t, float4& cur, float4& nxt) {
            // phi_t + publish
            float ph0 = ftanh(h[0]), ph1 = ftanh(h[1]);
            float ph2 = ftanh(h[2]), ph3 = ftanh(h[3]);
            *(float4*)&phi_lds[t & 1][s0] = float4{ph0, ph1, ph2, ph3};

            // kappa partials over 4 states
            float red[8];
            #pragma unroll
            for (int r = 0; r < 8; ++r)
                red[r] = __builtin_fmaf(ph0, WV[0][r],
                         __builtin_fmaf(ph1, WV[1][r],
                         __builtin_fmaf(ph2, WV[2][r], ph3 * WV[3][r])));
            #pragma unroll
            for (int r = 0; r < 8; ++r) red[r] = wave_red_sum(red[r]);
            if (lane == 63) {
                *(float4*)&part[t & 1][wid][0] = float4{red[0], red[1], red[2], red[3]};
                *(float4*)&part[t & 1][wid][4] = float4{red[4], red[5], red[6], red[7]};
            }
            // prefetch ext_{t+1} (written by helpers at iter t-1; visible)
            nxt = *(const float4*)&ext_lds[(t + 1) & 3][s0];
            lds_barrier();

            // stage 2: 64 partials -> kf in SGPRs
            float pv = (&part[t & 1][0][0])[s2addr];
            pv = red8(pv);
            float kf0 = readlane_f(pv, 7),  kf1 = readlane_f(pv, 15);
            float kf2 = readlane_f(pv, 23), kf3 = readlane_f(pv, 31);
            float kf4 = readlane_f(pv, 39), kf5 = readlane_f(pv, 47);
            float kf6 = readlane_f(pv, 55), kf7 = readlane_f(pv, 63);
            float ec[4] = {cur.x, cur.y, cur.z, cur.w};
            #pragma unroll
            for (int k = 0; k < 4; ++k) {
                float r0 = kf0 * WU[k][0];
                r0 = __builtin_fmaf(kf1, WU[k][1], r0);
                r0 = __builtin_fmaf(kf2, WU[k][2], r0);
                r0 = __builtin_fmaf(kf3, WU[k][3], r0);
                float r1 = kf4 * WU[k][4];
                r1 = __builtin_fmaf(kf5, WU[k][5], r1);
                r1 = __builtin_fmaf(kf6, WU[k][6], r1);
                r1 = __builtin_fmaf(kf7, WU[k][7], r1);
                h[k] = __builtin_fmaf(ONEMA, h[k], ec[k] + (r0 + r1));
            }
        };

        for (int t = 0; t < TSTEPS; t += 2) {
            MBODY(t,     eA, eB);
            MBODY(t + 1, eB, eA);
        }
        __builtin_amdgcn_s_setprio(0);

        // epilogue: publish phi_256 to slot 0
        {
            float4 ph = float4{ftanh(h[0]), ftanh(h[1]), ftanh(h[2]), ftanh(h[3])};
            *(float4*)&phi_lds[0][s0] = ph;
        }
        lds_barrier();
        lds_barrier();
    } else {
        // =========================== HELPER WAVES (4) ===========================
        const int hm = tid - 512;    // slot 0..255
        const int p  = hm >> 6;      // population (one per wave)
        const int s0 = hm * 8;       // 8 states per thread
        const int hw = wid - 8;

        float w_p;
        {
            float g0 = G[0], g1 = G[1], g2 = G[2], g3 = G[3];
            float mx = fmaxf(fmaxf(g0, g1), fmaxf(g2, g3));
            const float L2E = 1.4426950408889634f;
            float e0 = vexp2((g0 - mx) * L2E), e1 = vexp2((g1 - mx) * L2E);
            float e2 = vexp2((g2 - mx) * L2E), e3 = vexp2((g3 - mx) * L2E);
            float inv = vrcp(e0 + e1 + e2 + e3);
            float ap = (p == 0) ? e0 : (p == 1) ? e1 : (p == 2) ? e2 : e3;
            w_p = ap * inv * (1.0f / (float)RANDN);
        }

        // WI[k][i] = alpha*I (f=0..7), WO[k][o] = w*O (f=24..27)
        float WI[8][8], WO[8][4];
        #pragma unroll
        for (int c = 0; c < 8; ++c) {
            float mI = mu_lds[p * NF + c];
            #pragma unroll
            for (int k = 0; k < 8; ++k) WI[k][c] = mI;
        }
        #pragma unroll
        for (int c = 0; c < 4; ++c) {
            float mO = mu_lds[p * NF + 24 + c];
            #pragma unroll
            for (int k = 0; k < 8; ++k) WO[k][c] = mO;
        }
        #pragma unroll
        for (int pr = 0; pr < 4; ++pr) {
            float nlr[2][NF];
            #pragma unroll
            for (int kk = 0; kk < 2; ++kk) {
                const float4* src = (const float4*)(nl + (size_t)(s0 + pr * 2 + kk) * NF);
                #pragma unroll
                for (int q = 0; q < 7; ++q) {
                    float4 v = src[q];
                    nlr[kk][q*4+0] = v.x; nlr[kk][q*4+1] = v.y;
                    nlr[kk][q*4+2] = v.z; nlr[kk][q*4+3] = v.w;
                }
            }
            #pragma unroll
            for (int f = 0; f < 12; ++f) {
                int rf = (f < 8) ? f : (16 + f);
                const float4* cr = (const float4*)&c_lds[(p * NF + rf) * NF];
                float crow[NF];
                #pragma unroll
                for (int q = 0; q < 7; ++q) {
                    float4 v = cr[q];
                    crow[q*4+0] = v.x; crow[q*4+1] = v.y;
                    crow[q*4+2] = v.z; crow[q*4+3] = v.w;
                }
                #pragma unroll
                for (int kk = 0; kk < 2; ++kk) {
                    float acc = (f < 8) ? WI[pr*2+kk][f] : WO[pr*2+kk][f-8];
                    #pragma unroll
                    for (int ss = 0; ss < NF; ++ss)
                        acc = __builtin_fmaf(crow[ss], nlr[kk][ss], acc);
                    if (f < 8) WI[pr*2+kk][f] = acc; else WO[pr*2+kk][f-8] = acc;
                }
            }
        }
        #pragma unroll
        for (int k = 0; k < 8; ++k) {
            #pragma unroll
            for (int c = 0; c < 8; ++c) WI[k][c] *= ALPHA;
            #pragma unroll
            for (int c = 0; c < 4; ++c) WO[k][c] *= w_p;
        }

        const float4* nbase = (const float4*)nrec + (size_t)b * (TSTEPS * NSTATES / 4) + hm * 2;

        // prologue: ext_0, ext_1 (direct noise loads), then prefetch noise_2/3
        #pragma unroll
        for (int t0 = 0; t0 < 2; ++t0) {
            float4 m0 = nbase[(size_t)t0 * (NSTATES / 4)];
            float4 m1 = nbase[(size_t)t0 * (NSTATES / 4) + 1];
            const float4* up = (const float4*)&u_lds[t0 * NI];
            float4 ua = up[0], ub = up[1];
            float ut2[8] = {ua.x, ua.y, ua.z, ua.w, ub.x, ub.y, ub.z, ub.w};
            float nn[8] = {m0.x, m0.y, m0.z, m0.w, m1.x, m1.y, m1.z, m1.w};
            float ex[8];
            #pragma unroll
            for (int k = 0; k < 8; ++k) {
                float a = ALPHA * nn[k];
                #pragma unroll
                for (int i = 0; i < 8; ++i) a = __builtin_fmaf(ut2[i], WI[k][i], a);
                ex[k] = a;
            }
            float4* ew = (float4*)&ext_lds[t0][s0];
            ew[0] = float4{ex[0], ex[1], ex[2], ex[3]};
            ew[1] = float4{ex[4], ex[5], ex[6], ex[7]};
        }
        float4 nA0 = nbase[2 * (NSTATES / 4)], nA1 = nbase[2 * (NSTATES / 4) + 1];
        float4 nB0 = nbase[3 * (NSTATES / 4)], nB1 = nbase[3 * (NSTATES / 4) + 1];
        __syncthreads();   // ext_0/1 visible to main

        auto YPART = [&](int t_phi, int slot, int row) {
            const float4* pp = (const float4*)&phi_lds[slot][s0];
            float4 p0 = pp[0], p1 = pp[1];
            float ph[8] = {p0.x, p0.y, p0.z, p0.w, p1.x, p1.y, p1.z, p1.w};
            float yr[4];
            #pragma unroll
            for (int o = 0; o < 4; ++o) {
                float a = ph[0] * WO[0][o];
                #pragma unroll
                for (int k = 1; k < 8; ++k) a = __builtin_fmaf(ph[k], WO[k][o], a);
                yr[o] = a;
            }
            #pragma unroll
            for (int o = 0; o < 4; ++o) yr[o] = wave_red_sum(yr[o]);
            if (lane == 63)
                *(float4*)&ybuf[row][hw][0] = float4{yr[0], yr[1], yr[2], yr[3]};
            (void)t_phi;
        };

        auto HBODY = [&](int t, float4& n0, float4& n1) {
            // y partials for step t-1 (garbage at t=0 -> dummy row 0)
            YPART(t - 1, (t + 1) & 1, t);
            if (t < TSTEPS - 2) {
                // ext_{t+2} from noise regs (issued at t-2) + drive
                const float4* up = (const float4*)&u_lds[(t + 2) * NI];
                float4 ua = up[0], ub = up[1];
                float ut2[8] = {ua.x, ua.y, ua.z, ua.w, ub.x, ub.y, ub.z, ub.w};
                float nn[8] = {n0.x, n0.y, n0.z, n0.w, n1.x, n1.y, n1.z, n1.w};
                float ex[8];
                #pragma unroll
                for (int k = 0; k < 8; ++k) {
                    float a = ALPHA * nn[k];
                    #pragma unroll
                    for (int i = 0; i < 8; ++i) a = __builtin_fmaf(ut2[i], WI[k][i], a);
                    ex[k] = a;
                }
                float4* ew = (float4*)&ext_lds[(t + 2) & 3][s0];
                ew[0] = float4{ex[0], ex[1], ex[2], ex[3]};
                ew[1] = float4{ex[4], ex[5], ex[6], ex[7]};
            }
            int tl = (t + 4 < TSTEPS) ? (t + 4) : (TSTEPS - 1);
            n0 = nbase[(size_t)tl * (NSTATES / 4)];
            n1 = nbase[(size_t)tl * (NSTATES / 4) + 1];
            lds_barrier();
        };

        for (int t = 0; t < TSTEPS; t += 2) {
            HBODY(t,     nA0, nA1);
            HBODY(t + 1, nB0, nB1);
        }

        // epilogue A: y_255 (phi_255, slot 1)
        YPART(255, 1, 256);
        lds_barrier();
        // epilogue B: y_256 (phi_256, slot 0, published by main)
        YPART(256, 0, 257);
        lds_barrier();
    }

    // ---- final y writeout: 1028 outputs, sum of 4 helper-wave partials ----
    for (int idx = tid; idx < (TSTEPS + 1) * NO; idx += THREADS) {
        int t = idx >> 2, o = idx & 3;
        yout[idx] = (ybuf[t + 1][0][o] + ybuf[t + 1][1][o])
                  + (ybuf[t + 1][2][o] + ybuf[t + 1][3][o]);
    }
}

extern "C" void kernel_launch(void* const* d_in, const int* in_sizes, int n_in,
                              void* d_out, int out_size, void* d_ws, size_t ws_size,
                              hipStream_t stream) {
    const float* u    = (const float*)d_in[0];
    const float* G    = (const float*)d_in[1];
    const float* mu   = (const float*)d_in[2];
    const float* C    = (const float*)d_in[3];
    const float* h0   = (const float*)d_in[4];
    const float* nl   = (const float*)d_in[5];
    const float* nrec = (const float*)d_in[6];
    float* yp = (float*)d_out;

    rnn_fused<<<dim3(NBATCH), dim3(THREADS), 0, stream>>>(u, G, mu, C, h0, nl, nrec, yp);
}